// Round 11
// baseline (172.576 us; speedup 1.0000x reference)
//
#include <hip/hip_runtime.h>

typedef _Float16 f16;
typedef _Float16 f16x8 __attribute__((ext_vector_type(8)));
typedef _Float16 f16x4 __attribute__((ext_vector_type(4)));
typedef float f32x4 __attribute__((ext_vector_type(4)));

__device__ __forceinline__ float rcpf(float x) { return __builtin_amdgcn_rcpf(x); }

// ---------------- kernel 1: weight convert -> FRAGMENT-ORDERED layout ------
// Wt'[(nt*3+w)*8+kt][kq][ni][rl][8 halfs]
__global__ void __launch_bounds__(256) cvt_w(const float* __restrict__ Wr,
                                             const float* __restrict__ Wz,
                                             const float* __restrict__ Wh,
                                             f16* __restrict__ out) {
  int o = blockIdx.x * 256 + threadIdx.x;        // < 49152
  int rl = o & 15, ni = (o >> 4) & 3, kq = (o >> 6) & 3, kt = (o >> 8) & 7;
  int wnt = o >> 11;
  int w = wnt % 3, nt = wnt / 3;
  int n = nt * 64 + ni * 16 + rl;
  int k0 = kt * 32 + kq * 8;
  const float* W = (w == 0) ? Wr : ((w == 1) ? Wz : Wh);
  f16x8 v;
#pragma unroll
  for (int e = 0; e < 8; ++e) v[e] = (f16)W[(size_t)(k0 + e) * 512 + n];
  *(f16x8*)(out + (size_t)o * 8) = v;
}

// ---------------- kernel 2: x convert f32->f16, FRAGMENT-ORDERED -----------
// Xf'[m16*8+kt][kq][rl][8 halfs]; full 128-batch in one launch (8192 blocks)
__global__ void __launch_bounds__(256) cvt_x(const float* __restrict__ in,
                                             f16* __restrict__ out) {
  int o = blockIdx.x * 256 + threadIdx.x;        // < 2097152
  int rl = o & 15, kq = (o >> 4) & 3, kt = (o >> 6) & 7, m16 = o >> 9;
  const float* src = in + (size_t)(m16 * 16 + rl) * 256 + kt * 32 + kq * 8;
  f16x8 v;
#pragma unroll
  for (int e = 0; e < 8; ++e) v[e] = (f16)src[e];
  *(f16x8*)(out + (size_t)o * 8) = v;
}

// ---------------- kernel 3: fused streaming-GEMM + scan --------------------
// Block = (b, hs: h-slice of 128), grid 512, 4 waves (1x4: wave = 64t x 32h).
// Per t-tile of 64 (mt = 0..7): barrier-free register-streamed GEMM from
// fragment-ordered Xf/Bf (L2/L3-resident) -> epilogue to LDS P (48 KB,
// chunked [w][tg8][h128][8t]) -> barrier -> 128 threads scan 64 t-steps
// (h-state in registers across phases) -> barrier. P never touches HBM.
// 2 blocks/CU co-resident: one block's serial scan hides under the other's
// GEMM.
__global__ void __launch_bounds__(256, 2) brc_fused(
    const f16* __restrict__ Af, const f16* __restrict__ Bf,
    const float* __restrict__ h0, const float* __restrict__ mr,
    const float* __restrict__ mz, const float* __restrict__ br,
    const float* __restrict__ bz, float* __restrict__ out) {
  __shared__ __align__(16) f16 Pl[24576];        // 48 KB
  const int tid = threadIdx.x;
  const int wid = tid >> 6, lane = tid & 63;
  const int bid = blockIdx.x;
  const int lid = (bid & 7) * 64 + (bid >> 3);   // bijective XCD swizzle
  const int b = lid >> 2, hs = lid & 3;          // 4 hs-blocks of a b adjacent
  const int wc = wid;                            // 1x4 wave grid

  // A: frag = (b*32 + mt*4 + mi)*8 + kt; byte = frag*1024 + lane*16
  const char* Ap = (const char*)Af + lane * 16;
  // B: wave covers h = hs*128 + wc*32 .. +32: nt = hs*2 + (wc>>1), nig = wc&1
  const int nt_w = hs * 2 + (wc >> 1);
  const char* Bp = (const char*)Bf + (lane >> 4) * 1024 + (lane & 15) * 16 +
                   (wc & 1) * 512;

  // scan state (threads 0..127 own chain h = hs*128 + tid)
  float h = 0.f, mrc = 0.f, mzc = 0.f, br2 = 0.f, nbz = 0.f;
  if (tid < 128) {
    int hg = hs * 128 + tid;
    h = h0[(size_t)b * 512 + hg];
    mrc = 2.0f * mr[hg]; mzc = -mz[hg];
    br2 = 2.0f * br[hg]; nbz = -bz[hg];
  }

  const int col = lane & 15, rbase = (lane >> 4) * 4;

  for (int mt = 0; mt < 8; ++mt) {
    f32x4 acc[3][4][2] = {};
#pragma unroll
    for (int kt = 0; kt < 8; ++kt) {
      f16x8 a[4], bfr[3][2];
#pragma unroll
      for (int mi = 0; mi < 4; ++mi)
        a[mi] = *(const f16x8*)(Ap +
                 (size_t)((b * 32 + mt * 4 + mi) * 8 + kt) * 1024);
#pragma unroll
      for (int w = 0; w < 3; ++w)
#pragma unroll
        for (int ni = 0; ni < 2; ++ni)
          bfr[w][ni] = *(const f16x8*)(Bp +
                        (size_t)((nt_w * 3 + w) * 8 + kt) * 4096 + ni * 256);
#pragma unroll
      for (int w = 0; w < 3; ++w)
#pragma unroll
        for (int mi = 0; mi < 4; ++mi)
#pragma unroll
          for (int ni = 0; ni < 2; ++ni)
            acc[w][mi][ni] = __builtin_amdgcn_mfma_f32_16x16x32_f16(
                a[mi], bfr[w][ni], acc[w][mi][ni], 0, 0, 0);
    }
    // ---- epilogue: acc -> LDS P. C/D: col=lane&15, t-row=(lane>>4)*4+r ----
#pragma unroll
    for (int w = 0; w < 3; ++w)
#pragma unroll
      for (int mi = 0; mi < 4; ++mi) {
        int t = mi * 16 + rbase;                 // 0..63 within tile
#pragma unroll
        for (int ni = 0; ni < 2; ++ni) {
          int hl = wc * 32 + ni * 16 + col;      // 0..127
          f16x4 v;
#pragma unroll
          for (int r = 0; r < 4; ++r) v[r] = (f16)acc[w][mi][ni][r];
          *(f16x4*)&Pl[w * 8192 + (t >> 3) * 1024 + hl * 8 + (t & 7)] = v;
        }
      }
    __syncthreads();                             // P visible to scan threads
    // ---- scan 64 t-steps (threads 0..127) ----
    if (tid < 128) {
      const f16* Pr_ = Pl + tid * 8;
      const f16* Pz_ = Pl + 8192 + tid * 8;
      const f16* Ph_ = Pl + 16384 + tid * 8;
      float* opm = out + ((size_t)b * 512 + mt * 64) * 512 + hs * 128 + tid;
      f16x8 Ra, Za, Ha, Rb, Zb, Hb;
#define LOADL(R, Z, Hh, g)                                              \
      do {                                                              \
        R  = *(const f16x8*)(Pr_ + (g) * 1024);                         \
        Z  = *(const f16x8*)(Pz_ + (g) * 1024);                         \
        Hh = *(const f16x8*)(Ph_ + (g) * 1024);                         \
      } while (0)
#define STEP8(R, Z, Hh, g)                                              \
      do {                                                              \
        _Pragma("unroll") for (int j = 0; j < 8; ++j) {                 \
          float prs = fmaf((float)R[j], 2.0f, br2);                     \
          float pzs = fmaf((float)Z[j], -1.0f, nbz);                    \
          float ph2 = (float)Hh[j] * 2.0f;                              \
          float er = __expf(fmaf(h, mrc, prs));                         \
          float rr = fmaf(-2.0f, rcpf(er + 1.0f), 2.0f);                \
          float ez = __expf(fmaf(h, mzc, pzs));                         \
          float zz = rcpf(1.0f + ez);                                   \
          float h2v = h + h;                                            \
          float ec = __expf(fmaf(rr, h2v, ph2));                        \
          float cd = fmaf(-2.0f, rcpf(ec + 1.0f), 1.0f);                \
          h = fmaf(zz, h - cd, cd);                                     \
          __builtin_nontemporal_store(h, opm + (size_t)((g) * 8 + j) * 512); \
        }                                                               \
      } while (0)
      LOADL(Ra, Za, Ha, 0);
#pragma unroll
      for (int g = 0; g < 8; g += 2) {
        LOADL(Rb, Zb, Hb, g + 1);
        STEP8(Ra, Za, Ha, g);
        if (g + 2 < 8) LOADL(Ra, Za, Ha, g + 2);
        STEP8(Rb, Zb, Hb, g + 1);
      }
#undef LOADL
#undef STEP8
    }
    __syncthreads();                             // scan done; P_lds reusable
  }
}

// ---------------- launch ----------------
extern "C" void kernel_launch(void* const* d_in, const int* in_sizes, int n_in,
                              void* d_out, int out_size, void* d_ws, size_t ws_size,
                              hipStream_t stream) {
  const float* x  = (const float*)d_in[0];
  const float* h0 = (const float*)d_in[1];
  const float* kr = (const float*)d_in[2];
  const float* kz = (const float*)d_in[3];
  const float* kh = (const float*)d_in[4];
  const float* mr = (const float*)d_in[5];
  const float* mz = (const float*)d_in[6];
  const float* br = (const float*)d_in[7];
  const float* bz = (const float*)d_in[8];
  float* out = (float*)d_out;

  f16* Bf = (f16*)d_ws;                 // 393216 halfs = 786 KB
  f16* Xf = Bf + 393216;                // 33.5M halfs = 67 MB

  cvt_w<<<192, 256, 0, stream>>>(kr, kz, kh, Bf);
  cvt_x<<<8192, 256, 0, stream>>>(x, Xf);
  brc_fused<<<512, 256, 0, stream>>>(Xf, Bf, h0, mr, mz, br, bz, out);
}

// Round 12
// 116.530 us; speedup vs baseline: 1.4810x; 1.4810x over previous
//
#include <hip/hip_runtime.h>

typedef _Float16 f16;
typedef _Float16 f16x8 __attribute__((ext_vector_type(8)));
typedef _Float16 f16x4 __attribute__((ext_vector_type(4)));
typedef float f32x4 __attribute__((ext_vector_type(4)));

__device__ __forceinline__ float rcpf(float x) { return __builtin_amdgcn_rcpf(x); }

// ---------------- kernel 1: weight convert -> FRAGMENT-ORDERED layout ------
// Wt'[(nt*3+w)*8+kt][kq][ni][rl][8 halfs]
__global__ void __launch_bounds__(256) cvt_w(const float* __restrict__ Wr,
                                             const float* __restrict__ Wz,
                                             const float* __restrict__ Wh,
                                             f16* __restrict__ out) {
  int o = blockIdx.x * 256 + threadIdx.x;        // < 49152
  int rl = o & 15, ni = (o >> 4) & 3, kq = (o >> 6) & 3, kt = (o >> 8) & 7;
  int wnt = o >> 11;
  int w = wnt % 3, nt = wnt / 3;
  int n = nt * 64 + ni * 16 + rl;
  int k0 = kt * 32 + kq * 8;
  const float* W = (w == 0) ? Wr : ((w == 1) ? Wz : Wh);
  f16x8 v;
#pragma unroll
  for (int e = 0; e < 8; ++e) v[e] = (f16)W[(size_t)(k0 + e) * 512 + n];
  *(f16x8*)(out + (size_t)o * 8) = v;
}

// ---------------- kernel 2: x convert f32->f16, FRAGMENT-ORDERED -----------
// Xf'[m16*8+kt][kq][rl][8 halfs]
__global__ void __launch_bounds__(256) cvt_x(const float* __restrict__ in,
                                             f16* __restrict__ out) {
  int o = blockIdx.x * 256 + threadIdx.x;        // < 2097152
  int rl = o & 15, kq = (o >> 4) & 3, kt = (o >> 6) & 7, m16 = o >> 9;
  const float* src = in + (size_t)(m16 * 16 + rl) * 256 + kt * 32 + kq * 8;
  f16x8 v;
#pragma unroll
  for (int e = 0; e < 8; ++e) v[e] = (f16)src[e];
  *(f16x8*)(out + (size_t)o * 8) = v;
}

// ---------------- kernel 3: producer/consumer fused GEMM + scan ------------
// Block = (b, hs: 128-h slice), grid 512, 512 threads = 8 waves.
// Waves 0..5 (producers): register-streamed GEMM of t-tile 32 (phase p+1)
//   into LDS P buffer (p+1)&1. Wave j: weight w3=j>>1, h-half hh=j&1,
//   tile 32t x 64h, acc[2][4].
// Waves 6,7 (consumers): scan 32 t-steps of phase p from buffer p&1,
//   one chain per thread (128 chains), write out directly.
// One __syncthreads per phase; double-buffered P (2 x 24.5 KB = 49 KB)
// -> 2 blocks/CU; consumer VALU overlaps producer MFMA (separate pipes).
// P never touches HBM.
__global__ void __launch_bounds__(512, 4) brc_fused(
    const f16* __restrict__ Af, const f16* __restrict__ Bf,
    const float* __restrict__ h0, const float* __restrict__ mr,
    const float* __restrict__ mz, const float* __restrict__ br,
    const float* __restrict__ bz, float* __restrict__ out) {
  __shared__ __align__(16) f16 Pl[2][12288];     // [buf][w3*4096+tg*1024+hl*8+t7]
  const int tid = threadIdx.x;
  const int wid = tid >> 6, lane = tid & 63;
  const int bid = blockIdx.x;
  const int lid = (bid & 7) * 64 + (bid >> 3);   // bijective XCD swizzle
  const int b = lid >> 2, hs = lid & 3;          // 4 hs-blocks of a b adjacent

  // ---- producer constants (waves 0..5) ----
  const int w3 = wid >> 1, hh = wid & 1;
  const int nt = hs * 2 + hh;
  const char* Ap = (const char*)Af + lane * 16;
  const char* Bp = (const char*)Bf + (lane >> 4) * 1024 + (lane & 15) * 16;
  const int col = lane & 15, rbase = (lane >> 4) * 4;

  // ---- consumer state (waves 6,7): chain c = tid & 127 ----
  const int c = tid & 127;
  const int hg = hs * 128 + c;
  float h = h0[(size_t)b * 512 + hg];
  const float mrc = 2.0f * mr[hg], mzc = -mz[hg];
  const float br2 = 2.0f * br[hg], nbz = -bz[hg];

  auto gemm_phase = [&](int q) {
    f16* Pb = Pl[q & 1];
    f32x4 acc[2][4] = {};
#pragma unroll
    for (int kt = 0; kt < 8; ++kt) {
      f16x8 a[2], bfr[4];
#pragma unroll
      for (int mi = 0; mi < 2; ++mi)
        a[mi] = *(const f16x8*)(Ap +
                 (size_t)((b * 32 + q * 2 + mi) * 8 + kt) * 1024);
#pragma unroll
      for (int ni = 0; ni < 4; ++ni)
        bfr[ni] = *(const f16x8*)(Bp +
                   (size_t)((nt * 3 + w3) * 8 + kt) * 4096 + ni * 256);
#pragma unroll
      for (int mi = 0; mi < 2; ++mi)
#pragma unroll
        for (int ni = 0; ni < 4; ++ni)
          acc[mi][ni] = __builtin_amdgcn_mfma_f32_16x16x32_f16(
              a[mi], bfr[ni], acc[mi][ni], 0, 0, 0);
    }
#pragma unroll
    for (int mi = 0; mi < 2; ++mi) {
      int tl = mi * 16 + rbase;                  // 0..31
#pragma unroll
      for (int ni = 0; ni < 4; ++ni) {
        int hl = hh * 64 + ni * 16 + col;        // 0..127
        f16x4 v;
#pragma unroll
        for (int r = 0; r < 4; ++r) v[r] = (f16)acc[mi][ni][r];
        *(f16x4*)&Pb[w3 * 4096 + (tl >> 3) * 1024 + hl * 8 + (tl & 7)] = v;
      }
    }
  };

  if (wid < 6) gemm_phase(0);                    // prologue

  for (int p = 0; p < 16; ++p) {
    __syncthreads();                             // buf[p&1] ready; other free
    if (wid < 6) {
      if (p + 1 < 16) gemm_phase(p + 1);
    } else {
      const f16* Pr_ = &Pl[p & 1][c * 8];
      const f16* Pz_ = Pr_ + 4096;
      const f16* Ph_ = Pr_ + 8192;
      float* opm = out + ((size_t)b * 512 + p * 32) * 512 + hg;
#pragma unroll
      for (int g = 0; g < 4; ++g) {
        f16x8 R  = *(const f16x8*)(Pr_ + g * 1024);
        f16x8 Z  = *(const f16x8*)(Pz_ + g * 1024);
        f16x8 Hh = *(const f16x8*)(Ph_ + g * 1024);
#pragma unroll
        for (int j = 0; j < 8; ++j) {
          float prs = fmaf((float)R[j], 2.0f, br2);
          float pzs = fmaf((float)Z[j], -1.0f, nbz);
          float ph2 = (float)Hh[j] * 2.0f;
          float er = __expf(fmaf(h, mrc, prs));
          float rr = fmaf(-2.0f, rcpf(er + 1.0f), 2.0f);
          float ez = __expf(fmaf(h, mzc, pzs));
          float zz = rcpf(1.0f + ez);
          float ec = __expf(fmaf(rr, h + h, ph2));
          float cd = fmaf(-2.0f, rcpf(ec + 1.0f), 1.0f);
          h = fmaf(zz, h - cd, cd);
          __builtin_nontemporal_store(h, opm + (size_t)(g * 8 + j) * 512);
        }
      }
    }
  }
}

// ---------------- launch ----------------
extern "C" void kernel_launch(void* const* d_in, const int* in_sizes, int n_in,
                              void* d_out, int out_size, void* d_ws, size_t ws_size,
                              hipStream_t stream) {
  const float* x  = (const float*)d_in[0];
  const float* h0 = (const float*)d_in[1];
  const float* kr = (const float*)d_in[2];
  const float* kz = (const float*)d_in[3];
  const float* kh = (const float*)d_in[4];
  const float* mr = (const float*)d_in[5];
  const float* mz = (const float*)d_in[6];
  const float* br = (const float*)d_in[7];
  const float* bz = (const float*)d_in[8];
  float* out = (float*)d_out;

  f16* Bf = (f16*)d_ws;                 // 393216 halfs = 786 KB
  f16* Xf = Bf + 393216;                // 16.8M halfs = 33.5 MB

  cvt_w<<<192, 256, 0, stream>>>(kr, kz, kh, Bf);
  cvt_x<<<8192, 256, 0, stream>>>(x, Xf);
  brc_fused<<<512, 512, 0, stream>>>(Xf, Bf, h0, mr, mz, br, bz, out);
}